// Round 1
// baseline (670.850 us; speedup 1.0000x reference)
//
#include <hip/hip_runtime.h>

// Varifold loss on MI355X.
// Reference: per sample, Kss + Ktt - 2*Kst with
//   k(x,y) = Lx*Ly * exp(-gamma*|Cx-Cy|^2) * <Nx,Ny>^2
// Folded form: combined face set (pred w=+1, targ w=-1), u = w*L:
//   total_b = sum_ij exp(-gamma*d2_ij) * (Nn_i . Nn_j)^2 * u_i * u_j
// out = (sum_b total_b) / B

#define NVERT 5023
#define NFACE 9976
#define BATCH 4
#define NT (2 * NFACE)          // 19952 faces per batch (pred + targ)
#define JCHUNKS 8

constexpr float GAMMA = 1.0f / (0.03f * 0.03f);   // 1111.111...
constexpr float EPSV  = 1e-12f;

// Per-face record: 2 x float4: {Cx,Cy,Cz,cq=-gamma*|C|^2}, {Nnx,Nny,Nnz,u=w*L}

__global__ __launch_bounds__(256)
void face_quant_kernel(const float* __restrict__ pred,
                       const float* __restrict__ targ,
                       const int*   __restrict__ faces,
                       float4*      __restrict__ fd,
                       float*       __restrict__ out) {
    int idx = blockIdx.x * 256 + threadIdx.x;
    if (idx == 0) out[0] = 0.0f;   // zero output before pair_sum (same stream)
    const int total = BATCH * NT;
    if (idx >= total) return;

    int b     = idx / NT;
    int r     = idx - b * NT;
    int which = (r >= NFACE) ? 1 : 0;      // 0 = pred, 1 = targ
    int f     = r - which * NFACE;

    const float* V = (which ? targ : pred) + (size_t)b * NVERT * 3;
    int i0 = faces[f * 3 + 0];
    int i1 = faces[f * 3 + 1];
    int i2 = faces[f * 3 + 2];

    float v0x = V[i0 * 3 + 0], v0y = V[i0 * 3 + 1], v0z = V[i0 * 3 + 2];
    float v1x = V[i1 * 3 + 0], v1y = V[i1 * 3 + 1], v1z = V[i1 * 3 + 2];
    float v2x = V[i2 * 3 + 0], v2y = V[i2 * 3 + 1], v2z = V[i2 * 3 + 2];

    const float third = 1.0f / 3.0f;
    float cx = (v0x + v1x + v2x) * third;
    float cy = (v0y + v1y + v2y) * third;
    float cz = (v0z + v1z + v2z) * third;

    float e1x = v1x - v0x, e1y = v1y - v0y, e1z = v1z - v0z;
    float e2x = v2x - v0x, e2y = v2y - v0y, e2z = v2z - v0z;

    float nx = 0.5f * (e1y * e2z - e1z * e2y);
    float ny = 0.5f * (e1z * e2x - e1x * e2z);
    float nz = 0.5f * (e1x * e2y - e1y * e2x);

    float L   = sqrtf(nx * nx + ny * ny + nz * nz);
    float inv = 1.0f / fmaxf(L, EPSV);
    float nnx = nx * inv, nny = ny * inv, nnz = nz * inv;

    float u  = which ? -L : L;                       // sign folds the -2*Kst
    float cq = -GAMMA * (cx * cx + cy * cy + cz * cz);

    fd[(size_t)idx * 2 + 0] = make_float4(cx, cy, cz, cq);
    fd[(size_t)idx * 2 + 1] = make_float4(nnx, nny, nnz, u);
}

__global__ __launch_bounds__(256)
void pair_sum_kernel(const float4* __restrict__ fd,
                     float*        __restrict__ out) {
    const int b = blockIdx.z;
    const float4* base = fd + (size_t)b * NT * 2;

    int i = blockIdx.x * 256 + threadIdx.x;
    float4 ci = make_float4(0.f, 0.f, 0.f, 0.f);
    float4 ni = make_float4(0.f, 0.f, 0.f, 0.f);
    if (i < NT) {
        ci = base[(size_t)i * 2 + 0];
        ni = base[(size_t)i * 2 + 1];
    }
    // hoisted per-i quantities
    const float Ax = 2.0f * GAMMA * ci.x;
    const float Ay = 2.0f * GAMMA * ci.y;
    const float Az = 2.0f * GAMMA * ci.z;
    const float cqi = ci.w;

    const int len = (NT + JCHUNKS - 1) / JCHUNKS;     // 2494
    const int j0 = blockIdx.y * len;
    const int j1 = min(NT, j0 + len);

    float acc = 0.0f;
    #pragma unroll 4
    for (int j = j0; j < j1; ++j) {
        // j is wave-uniform -> compiler emits scalar loads (s_load_dwordx4)
        float4 cj = base[(size_t)j * 2 + 0];
        float4 nj = base[(size_t)j * 2 + 1];

        float t = cqi + cj.w;                 // -gamma*(|Ci|^2+|Cj|^2)
        t = fmaf(Ax, cj.x, t);                // + 2*gamma*Ci.Cj
        t = fmaf(Ay, cj.y, t);
        t = fmaf(Az, cj.z, t);

        float d = ni.x * nj.x;
        d = fmaf(ni.y, nj.y, d);
        d = fmaf(ni.z, nj.z, d);

        float e = __expf(t);                  // v_exp_f32 fast path
        float p = d * d;
        acc = fmaf(e, p * nj.w, acc);         // u_j folded here
    }
    acc *= ni.w;                              // u_i hoisted (0 for padded i)

    // wave (64-lane) reduction then cross-wave via LDS
    #pragma unroll
    for (int off = 32; off > 0; off >>= 1)
        acc += __shfl_down(acc, off, 64);

    __shared__ float wsum[4];
    int lane = threadIdx.x & 63;
    int wv   = threadIdx.x >> 6;
    if (lane == 0) wsum[wv] = acc;
    __syncthreads();
    if (threadIdx.x == 0) {
        float s = wsum[0] + wsum[1] + wsum[2] + wsum[3];
        atomicAdd(out, s * (1.0f / BATCH));
    }
}

extern "C" void kernel_launch(void* const* d_in, const int* in_sizes, int n_in,
                              void* d_out, int out_size, void* d_ws, size_t ws_size,
                              hipStream_t stream) {
    const float* pred  = (const float*)d_in[0];
    const float* targ  = (const float*)d_in[1];
    const int*   faces = (const int*)d_in[2];
    float*       out   = (float*)d_out;
    float4*      fd    = (float4*)d_ws;     // BATCH*NT*2 float4 = ~2.55 MB

    const int totalFaces = BATCH * NT;
    face_quant_kernel<<<(totalFaces + 255) / 256, 256, 0, stream>>>(
        pred, targ, faces, fd, out);

    dim3 grid((NT + 255) / 256, JCHUNKS, BATCH);
    pair_sum_kernel<<<grid, 256, 0, stream>>>(fd, out);
}

// Round 3
// 279.948 us; speedup vs baseline: 2.3963x; 2.3963x over previous
//
#include <hip/hip_runtime.h>

// Varifold loss, round 3: symmetry-halved tile enumeration + exp2-domain
// exponent + magnitude-folded normals (sign handled structurally via padding).
// Fix vs R2: __exp2f -> __builtin_amdgcn_exp2f (raw v_exp_f32).
//
// Per-face record (2 x float4):
//   rec0 = {Cx, Cy, Cz, cq = -gamma*log2e*|C|^2}
//   rec1 = {mx, my, mz, unused}   with m = Nn * sqrt(L)
// Pair term: exp2(cq_i + cq_j + 2*gamma*log2e*<Ci,Cj>) * <m_i,m_j>^2
//   summed with uniform per-tile-pair factor  s_i*s_j * (ti==tj ? 1:2) / B.

#define NVERT 5023
#define NFACE 9976
#define BATCH 4
#define HALF  10240                 // pred slots padded to 40 tiles of 256
#define NTP   (2 * HALF)            // 20480 padded faces per batch
#define NTILES 80                   // NTP / 256
#define NPAIRS (NTILES * (NTILES + 1) / 2)   // 3240

constexpr float GAMMA = 1.0f / (0.03f * 0.03f);
constexpr float LOG2E = 1.4426950408889634f;
constexpr float EPSV  = 1e-12f;

__global__ __launch_bounds__(256)
void face_quant_kernel(const float* __restrict__ pred,
                       const float* __restrict__ targ,
                       const int*   __restrict__ faces,
                       float4*      __restrict__ fd,
                       float*       __restrict__ out) {
    int idx = blockIdx.x * 256 + threadIdx.x;
    if (idx == 0) out[0] = 0.0f;            // runs before pair_sum on stream
    const int total = BATCH * NTP;
    if (idx >= total) return;

    int b     = idx / NTP;
    int s     = idx - b * NTP;
    int which = (s >= HALF) ? 1 : 0;        // 0 = pred(+), 1 = targ(-)
    int f     = s - which * HALF;

    float4 r0 = make_float4(0.f, 0.f, 0.f, 0.f);
    float4 r1 = make_float4(0.f, 0.f, 0.f, 0.f);

    if (f < NFACE) {
        const float* V = (which ? targ : pred) + (size_t)b * NVERT * 3;
        int i0 = faces[f * 3 + 0];
        int i1 = faces[f * 3 + 1];
        int i2 = faces[f * 3 + 2];

        float v0x = V[i0*3+0], v0y = V[i0*3+1], v0z = V[i0*3+2];
        float v1x = V[i1*3+0], v1y = V[i1*3+1], v1z = V[i1*3+2];
        float v2x = V[i2*3+0], v2y = V[i2*3+1], v2z = V[i2*3+2];

        const float third = 1.0f / 3.0f;
        float cx = (v0x + v1x + v2x) * third;
        float cy = (v0y + v1y + v2y) * third;
        float cz = (v0z + v1z + v2z) * third;

        float e1x = v1x - v0x, e1y = v1y - v0y, e1z = v1z - v0z;
        float e2x = v2x - v0x, e2y = v2y - v0y, e2z = v2z - v0z;

        float nx = 0.5f * (e1y * e2z - e1z * e2y);
        float ny = 0.5f * (e1z * e2x - e1x * e2z);
        float nz = 0.5f * (e1x * e2y - e1y * e2x);

        float L   = sqrtf(nx*nx + ny*ny + nz*nz);
        float inv = 1.0f / fmaxf(L, EPSV);
        float sc  = inv * sqrtf(L);          // m = N/L * sqrt(L)

        float cq  = -GAMMA * LOG2E * (cx*cx + cy*cy + cz*cz);
        r0 = make_float4(cx, cy, cz, cq);
        r1 = make_float4(nx * sc, ny * sc, nz * sc, 0.f);
    }
    fd[(size_t)idx * 2 + 0] = r0;
    fd[(size_t)idx * 2 + 1] = r1;
}

__global__ __launch_bounds__(256)
void pair_sum_kernel(const float4* __restrict__ fd,
                     float*        __restrict__ out) {
    const int b  = blockIdx.z;
    const int tp = blockIdx.x;

    // decode upper-triangular tile pair (ti <= tj); <=80 SALU iterations
    int ti = 0, rem = tp;
    while (rem >= NTILES - ti) { rem -= NTILES - ti; ++ti; }
    int tj = ti + rem;

    const float4* base = fd + (size_t)b * NTP * 2;

    const int i = ti * 256 + threadIdx.x;
    float4 ci = base[(size_t)i * 2 + 0];
    float4 mi = base[(size_t)i * 2 + 1];

    const float TG  = 2.0f * GAMMA * LOG2E;
    const float Ax  = TG * ci.x;
    const float Ay  = TG * ci.y;
    const float Az  = TG * ci.z;
    const float cqi = ci.w;

    const int j0 = tj * 256;
    float acc = 0.0f;
    #pragma unroll 8
    for (int jj = 0; jj < 256; ++jj) {
        int j = j0 + jj;                      // wave-uniform -> s_load
        float4 cj = base[(size_t)j * 2 + 0];
        float4 mj = base[(size_t)j * 2 + 1];

        float t = cqi + cj.w;
        t = fmaf(Ax, cj.x, t);
        t = fmaf(Ay, cj.y, t);
        t = fmaf(Az, cj.z, t);

        float d = mi.x * mj.x;
        d = fmaf(mi.y, mj.y, d);
        d = fmaf(mi.z, mj.z, d);

        float e = __builtin_amdgcn_exp2f(t);  // v_exp_f32
        acc = fmaf(e, d * d, acc);
    }

    // uniform post-scale: signs, symmetry factor, 1/B
    float sgn = ((ti < NTILES/2) == (tj < NTILES/2)) ? 1.0f : -1.0f;
    float fac = sgn * ((ti == tj) ? 1.0f : 2.0f) * (1.0f / BATCH);
    acc *= fac;

    #pragma unroll
    for (int off = 32; off > 0; off >>= 1)
        acc += __shfl_down(acc, off, 64);

    __shared__ float wsum[4];
    int lane = threadIdx.x & 63;
    int wv   = threadIdx.x >> 6;
    if (lane == 0) wsum[wv] = acc;
    __syncthreads();
    if (threadIdx.x == 0) {
        atomicAdd(out, wsum[0] + wsum[1] + wsum[2] + wsum[3]);
    }
}

extern "C" void kernel_launch(void* const* d_in, const int* in_sizes, int n_in,
                              void* d_out, int out_size, void* d_ws, size_t ws_size,
                              hipStream_t stream) {
    const float* pred  = (const float*)d_in[0];
    const float* targ  = (const float*)d_in[1];
    const int*   faces = (const int*)d_in[2];
    float*       out   = (float*)d_out;
    float4*      fd    = (float4*)d_ws;      // BATCH*NTP*2 float4 = 2.62 MB

    const int totalSlots = BATCH * NTP;
    face_quant_kernel<<<(totalSlots + 255) / 256, 256, 0, stream>>>(
        pred, targ, faces, fd, out);

    dim3 grid(NPAIRS, 1, BATCH);
    pair_sum_kernel<<<grid, 256, 0, stream>>>(fd, out);
}